// Round 17
// baseline (30.796 us; speedup 1.0000x reference)
//
#include <hip/hip_runtime.h>

// Fully-fused 4-level db4 wavedec ('symmetric'), faithful to the JAX/pywt reference.
// x: [B=64, L=4096, C=32] f32. Out flat: cA4,cD4,cD3,cD2,cD1 each [B,C,len].
// lens: 4096 -> 2051 -> 1029 -> 518 -> 262.
// r17 "constant geometry": r16 base (direct global stores, 19.3 KB LDS,
// 8 blocks/CU, 3 barriers), but interior tiles (1..6) run a fully
// compile-time-constant path: spans 618/306/150/72/33 are literals, run
// partition is exact (51/25/36/16 runs of R=6/6/2/2 +1 tail), ownership is
// run-aligned so the store guard is one hoisted boolean per run. Boundary
// tiles 0/7 keep the dynamic+margin path with meshing owned ranges.

#define NT 256
#define NCHB 4

// Window-row pitches (floats), == 2 mod 4 (pitch/2 odd): b64 accesses spread
// 4 lanes/bank-pair (the wave64 b64 minimum).
#define LPX 634  // x span <= 618 (+6 left, +7 right margins)
#define LP1 322  // l1 span <= 306
#define LP2 166  // l2 span <= 150
#define LP3 86   // l3 span <= 72

#define L0C 4096
#define L1C 2051
#define L2C 1029
#define L3C 518
#define L4C 262
#define SC 2048

#define OFF_CD4 (SC * L4C)
#define OFF_CD3 (2 * SC * L4C)
#define OFF_CD2 (OFF_CD3 + SC * L3C)
#define OFF_CD1 (OFF_CD2 + SC * L2C)

__device__ __forceinline__ void filt8(
    const float w0, const float w1, const float w2, const float w3,
    const float w4, const float w5, const float w6, const float w7,
    float& a, float& d) {
    // db4 correlation kernels (dec_lo reversed = _H; dec_hi reversed), split trees.
    constexpr float FLO[8] = {
        0.23037781330885523f,  0.7148465705525415f,  0.6308807679295904f,
        -0.02798376941698385f, -0.18703481171888114f, 0.030841381835986965f,
        0.032883011666982945f, -0.010597401784997278f};
    constexpr float FHI[8] = {
        -0.010597401784997278f, -0.032883011666982945f, 0.030841381835986965f,
        0.18703481171888114f,  -0.02798376941698385f,  -0.6308807679295904f,
        0.7148465705525415f,   -0.23037781330885523f};
    float a0 = FLO[0] * w0;
    a0 = fmaf(FLO[1], w1, a0); a0 = fmaf(FLO[2], w2, a0); a0 = fmaf(FLO[3], w3, a0);
    float a1 = FLO[4] * w4;
    a1 = fmaf(FLO[5], w5, a1); a1 = fmaf(FLO[6], w6, a1); a1 = fmaf(FLO[7], w7, a1);
    a = a0 + a1;
    float d0 = FHI[0] * w0;
    d0 = fmaf(FHI[1], w1, d0); d0 = fmaf(FHI[2], w2, d0); d0 = fmaf(FHI[3], w3, d0);
    float d1 = FHI[4] * w4;
    d1 = fmaf(FHI[5], w5, d1); d1 = fmaf(FHI[6], w6, d1); d1 = fmaf(FHI[7], w7, d1);
    d = d0 + d1;
}

// ---------------- interior (constant-geometry) run ----------------
// srow: src + c*PS (sample t at word t - srclo + 6, srclo = 2*lo - 6 exactly).
// drow: dst + c*PD (next-level window, word rel+6). gcd/gca: abs output rows.
// SPAN/OLO/OHI compile-time; OLO/OHI are multiples of R -> whole-run store
// predicate, hoisted. REM==1 handled by slot NRUN (single tail output).
template <int R, int SPAN, int OLO, int OHI, bool LAST>
__device__ __forceinline__ void irun(
    const float* __restrict__ srow, float* __restrict__ drow,
    float* __restrict__ gcd, int lo, float* __restrict__ gca, int slot) {
    static_assert((R & 1) == 0, "R even");
    constexpr int NRUN = SPAN / R;
    constexpr int REM = SPAN - NRUN * R;  // 0 or 1
    if (REM && slot == NRUN) {
        constexpr int rel = SPAN - 1;
        const float* s = srow + 2 * rel + 6;
        float a, d;
        filt8(s[0], s[1], s[2], s[3], s[4], s[5], s[6], s[7], a, d);
        gcd[lo + rel] = d;
        if constexpr (LAST) gca[lo + rel] = a;
        else drow[rel + 6] = a;
        return;
    }
    if (slot >= NRUN) return;
    const int rel0 = slot * R;
    const float2* row2 = reinterpret_cast<const float2*>(srow);
    const int p = rel0 + 3;  // float2 idx of word 2*rel0+6 (first tap)
    float2 f0 = row2[p], f1 = row2[p + 1], f2 = row2[p + 2];
    const bool st = (rel0 >= OLO) && (rel0 + R <= OHI);
    float* g = gcd + lo + rel0;
    float ap = 0.f;
#pragma unroll
    for (int r = 0; r < R; ++r) {
        const float2 f3 = row2[p + 3 + r];
        float a, d;
        filt8(f0.x, f0.y, f1.x, f1.y, f2.x, f2.y, f3.x, f3.y, a, d);
        if (st) g[r] = d;
        if constexpr (LAST) {
            gca[lo + rel0 + r] = a;
        } else {
            if (r & 1)
                *reinterpret_cast<float2*>(drow + rel0 + r - 1 + 6) =
                    make_float2(ap, a);
            else
                ap = a;
        }
        f0 = f1; f1 = f2; f2 = f3;
    }
}

__device__ __forceinline__ void icascade(
    const float* bx, float* b1, float* b2, float* b3,
    float* __restrict__ out, int sigB, int c, int slot,
    int lo1, int lo2, int lo3, int lo4) {
    const int sig = sigB + c;
    float* gcd1 = out + OFF_CD1 + sig * L1C;
    float* gcd2 = out + OFF_CD2 + sig * L2C;
    float* gcd3 = out + OFF_CD3 + sig * L3C;
    float* gcd4 = out + OFF_CD4 + sig * L4C;
    float* gca4 = out + sig * L4C;

    irun<6, 306, 18, 282, false>(bx + c * LPX, b1 + c * LP1, gcd1, lo1, nullptr, slot);
    __syncthreads();
    irun<6, 150, 12, 144, false>(b1 + c * LP1, b2 + c * LP2, gcd2, lo2, nullptr, slot);
    __syncthreads();
    irun<2, 72, 4, 70, false>(b2 + c * LP2, b3 + c * LP3, gcd3, lo3, nullptr, slot);
    __syncthreads();
    irun<2, 33, 0, 34, true>(b3 + c * LP3, nullptr, gcd4, lo4, gca4, slot);
}

// ---------------- boundary (dynamic) run — r16 path ----------------
template <int R, bool LAST>
__device__ __forceinline__ void level_run(
    const float* __restrict__ src, int PS, int srclo,
    float* __restrict__ dst, int PD, int DL,
    int lo, int hi,
    float* __restrict__ gcd, int ownLo, int ownHi,
    float* __restrict__ gca,
    int c, int slot) {
    static_assert((R & 1) == 0, "R even");
    const int span = hi - lo;
    const int nrun = span / R;
    bool tail = false;
    int i0;
    if (slot < nrun) {
        i0 = lo + slot * R;
    } else if (slot == nrun && nrun * R < span) {
        i0 = lo + ((span - R) & ~1);
        tail = (span & 1) != 0;
    } else {
        return;
    }

    const float* rowb = src + c * PS;
    const float2* row2 = reinterpret_cast<const float2*>(rowb);
    const int p = i0 - (srclo >> 1);
    float2 f0 = row2[p], f1 = row2[p + 1], f2 = row2[p + 2];
    float* dbase = LAST ? nullptr : dst + c * PD;

    float ap = 0.f;
#pragma unroll
    for (int r = 0; r < R; ++r) {
        const float2 f3 = row2[p + 3 + r];
        const int i = i0 + r;
        float a, d;
        filt8(f0.x, f0.y, f1.x, f1.y, f2.x, f2.y, f3.x, f3.y, a, d);
        if (i >= ownLo && i < ownHi) gcd[i] = d;
        if constexpr (!LAST) {
            if (r & 1)
                *reinterpret_cast<float2*>(dbase + (i - 1 - lo) + 6) =
                    make_float2(ap, a);
            else
                ap = a;
            // reflection margins for the next level (boundary tiles only)
            if (lo == 0 && i < 6) dbase[5 - i] = a;
            if (hi == DL && i >= DL - 7) dbase[(2 * DL - 1 - i) - lo + 6] = a;
        } else {
            gca[i] = a;
        }
        f0 = f1; f1 = f2; f2 = f3;
    }
    if (tail) {
        const int i = hi - 1;
        const float* s = rowb + 6 - srclo;
        float a, d;
        filt8(s[2*i-6], s[2*i-5], s[2*i-4], s[2*i-3],
              s[2*i-2], s[2*i-1], s[2*i],   s[2*i+1], a, d);
        if (i >= ownLo && i < ownHi) gcd[i] = d;
        if constexpr (!LAST) {
            dbase[i - lo + 6] = a;
            if (hi == DL && i >= DL - 7) dbase[(2 * DL - 1 - i) - lo + 6] = a;
        } else {
            gca[i] = a;
        }
    }
}

__device__ __forceinline__ void bcascade(
    const float* bx, float* b1, float* b2, float* b3,
    float* __restrict__ out, int sigB, int tile, int c, int slot,
    int lox, int lo1, int hi1, int lo2, int hi2, int lo3, int hi3,
    int lo4, int hi4) {
    // owned ranges meshing with the interior run-aligned partition
    const int o1lo = (tile == 0) ? 0 : 1824;
    const int o1hi = (tile == 0) ? 240 : L1C;
    const int o2lo = (tile == 0) ? 0 : 918;
    const int o2hi = (tile == 0) ? 126 : L2C;
    const int o3lo = (tile == 0) ? 0 : 460;
    const int o3hi = (tile == 0) ? 64 : L3C;

    const int sig = sigB + c;
    float* gcd1 = out + OFF_CD1 + sig * L1C;
    float* gcd2 = out + OFF_CD2 + sig * L2C;
    float* gcd3 = out + OFF_CD3 + sig * L3C;
    float* gcd4 = out + OFF_CD4 + sig * L4C;
    float* gca4 = out + sig * L4C;

    level_run<6, false>(bx, LPX, lox, b1, LP1, L1C, lo1, hi1,
                        gcd1, o1lo, o1hi, nullptr, c, slot);
    __syncthreads();
    level_run<4, false>(b1, LP1, lo1, b2, LP2, L2C, lo2, hi2,
                        gcd2, o2lo, o2hi, nullptr, c, slot);
    __syncthreads();
    level_run<2, false>(b2, LP2, lo2, b3, LP3, L3C, lo3, hi3,
                        gcd3, o3lo, o3hi, nullptr, c, slot);
    __syncthreads();
    level_run<2, true>(b3, LP3, lo3, nullptr, 0, L4C, lo4, hi4,
                       gcd4, lo4, hi4, gca4, c, slot);
}

__global__ __launch_bounds__(NT, 8) void fused_dwt_kernel(
    const float* __restrict__ x, float* __restrict__ out) {
    __shared__ __align__(16) float bx[NCHB * LPX];
    __shared__ __align__(16) float b1[NCHB * LP1];
    __shared__ __align__(16) float b2[NCHB * LP2];
    __shared__ __align__(16) float b3[NCHB * LP3];

    // XCD swizzle: 4096 blocks = 8 XCDs x 512 contiguous works.
    const int bid = blockIdx.x;
    const int work = (bid & 7) * 512 + (bid >> 3);
    const int cg = work & 7;           // channel group 0..7 (4 ch each)
    const int tile = (work >> 3) & 7;  // cA4 tile 0..7
    const int b = work >> 6;           // batch 0..63

    const int tid = threadIdx.x;
    const int c = tid & 3;
    const int slot = tid >> 2;  // 0..63
    const int c0 = cg * 4;
    const int sigB = b * 32 + c0;

    const int lo4 = 33 * tile, hi4 = min(L4C, lo4 + 33);
    const int lo3 = max(0, 2 * lo4 - 6), hi3 = min(L3C, 2 * hi4);
    const int lo2 = max(0, 2 * lo3 - 6), hi2 = min(L2C, 2 * hi3);
    const int lo1 = max(0, 2 * lo2 - 6), hi1 = min(L1C, 2 * hi2);
    const int lox = max(0, 2 * lo1 - 6), hix = min(L0C, 2 * hi1);

    // ---- stage x tile into transposed rows (+ reflection margins) ----
    const float* xb = x + b * (L0C * 32) + c0;
    const int npair = (hix - lox) >> 1;
    for (int q = tid; q < npair; q += NT) {
        const int j = q << 1;
        const int t = lox + j;
        const float4 va = *reinterpret_cast<const float4*>(xb + t * 32);
        const float4 vb = *reinterpret_cast<const float4*>(xb + t * 32 + 32);
        const float av[4] = {va.x, va.y, va.z, va.w};
        const float bv[4] = {vb.x, vb.y, vb.z, vb.w};
#pragma unroll
        for (int hh = 0; hh < NCHB; ++hh)
            *reinterpret_cast<float2*>(bx + hh * LPX + 6 + j) =
                make_float2(av[hh], bv[hh]);
        if (lox == 0 && t < 6) {
#pragma unroll
            for (int hh = 0; hh < NCHB; ++hh) {
                bx[hh * LPX + 5 - t] = av[hh];
                if (t + 1 < 6) bx[hh * LPX + 4 - t] = bv[hh];
            }
        }
        if (hix == L0C && t + 1 >= L0C - 7) {
#pragma unroll
            for (int hh = 0; hh < NCHB; ++hh) {
                if (t >= L0C - 7) bx[hh * LPX + (2 * L0C - 1 - t) - lox + 6] = av[hh];
                bx[hh * LPX + (2 * L0C - 2 - t) - lox + 6] = bv[hh];
            }
        }
    }
    __syncthreads();

    if (tile == 0 || tile == 7)
        bcascade(bx, b1, b2, b3, out, sigB, tile, c, slot,
                 lox, lo1, hi1, lo2, hi2, lo3, hi3, lo4, hi4);
    else
        icascade(bx, b1, b2, b3, out, sigB, c, slot, lo1, lo2, lo3, lo4);
}

extern "C" void kernel_launch(void* const* d_in, const int* in_sizes, int n_in,
                              void* d_out, int out_size, void* d_ws, size_t ws_size,
                              hipStream_t stream) {
    (void)in_sizes; (void)n_in; (void)d_ws; (void)ws_size; (void)out_size;
    const float* x = (const float*)d_in[0];
    float* out = (float*)d_out;
    fused_dwt_kernel<<<dim3(4096), dim3(NT), 0, stream>>>(x, out);
}